// Round 1
// baseline (435.801 us; speedup 1.0000x reference)
//
#include <hip/hip_runtime.h>

typedef float f4 __attribute__((ext_vector_type(4)));
typedef short s8 __attribute__((ext_vector_type(8)));
typedef unsigned short u16x4 __attribute__((ext_vector_type(4)));

// ---- ws layout (bytes) ----
// att    : 0        .. 1 MiB   (4096*64 f32)
// embB   : 1 MiB    .. 5 MiB   (4096*512 bf16)
// rbT    : 5 MiB    .. 37 MiB  (64*512*512 bf16, [n][o][i])
// gemmT  : 37 MiB   .. 45 MiB  (512*4096 f32, [o][b])
// biasT  : 45 MiB   .. 53 MiB  (512*4096 f32, [o][b])

__device__ __forceinline__ unsigned short f2bf(float f) {
    unsigned int u = __float_as_uint(f);
    unsigned int r = (u + 0x7fffu + ((u >> 16) & 1u)) >> 16;
    return (unsigned short)r;
}

__global__ void gather_att(const int* __restrict__ ids, const float* __restrict__ rel_att,
                           float* __restrict__ att) {
    int g = blockIdx.x * 256 + threadIdx.x;       // 0 .. 4096*64-1
    int b = g >> 6, n = g & 63;
    att[g] = rel_att[(size_t)ids[b] * 64 + n];
}

__global__ void cvt_emb(const float* __restrict__ e, unsigned short* __restrict__ eb) {
    int g = (blockIdx.x * 256 + threadIdx.x) * 4;
    f4 v = *(const f4*)(e + g);
    u16x4 o;
    o[0] = f2bf(v[0]); o[1] = f2bf(v[1]); o[2] = f2bf(v[2]); o[3] = f2bf(v[3]);
    *(u16x4*)(eb + g) = o;
}

// rbT[n][o][i] = bf16(rel_base[n][i][o])
__global__ void transpose_rb(const float* __restrict__ rb, unsigned short* __restrict__ rbT) {
    __shared__ float tl[32][33];
    int n = blockIdx.z, i0 = blockIdx.x * 32, o0 = blockIdx.y * 32;
    int tx = threadIdx.x, ty = threadIdx.y;      // 32 x 8
#pragma unroll
    for (int k = 0; k < 4; k++) {
        int i = ty + k * 8;
        tl[i][tx] = rb[((size_t)(n * 512 + i0 + i)) * 512 + o0 + tx];
    }
    __syncthreads();
#pragma unroll
    for (int k = 0; k < 4; k++) {
        int o = ty + k * 8;
        rbT[((size_t)(n * 512 + o0 + o)) * 512 + i0 + tx] = f2bf(tl[tx][o]);
    }
}

// biasT[o][b] = sum_n att[b,n] * rel_bias[n,o]
__global__ __launch_bounds__(256) void bias_kernel(const float* __restrict__ att,
                                                   const float* __restrict__ relb,
                                                   float* __restrict__ bT) {
    __shared__ float aS[64][65];
    int t = threadIdx.x;
    int b0 = blockIdx.x * 64;
    int oq = blockIdx.y;                          // 0..3
#pragma unroll
    for (int k = 0; k < 16; k++) {
        int idx = t + 256 * k;
        aS[idx >> 6][idx & 63] = att[(size_t)(b0 + (idx >> 6)) * 64 + (idx & 63)];
    }
    __syncthreads();
    int b = t & 63, og = t >> 6;
    for (int op = 0; op < 32; op++) {
        int o = oq * 128 + og * 32 + op;
        float s = 0.f;
#pragma unroll
        for (int n = 0; n < 64; n++) s += aS[b][n] * relb[n * 512 + o];
        bT[(size_t)o * 4096 + b0 + b] = s;
    }
}

// Main fused GEMM: gemmT[o][b] = sum_n att[b,n] * sum_i emb[b,i]*rbT[n][o][i]
// block: 64 b (m) x 64 o; 4 waves, wave tile = 16 o x 64 m; K-chunks of 128 i.
__global__ __launch_bounds__(256, 2) void gemm_fold(const unsigned short* __restrict__ embB,
                                                    const unsigned short* __restrict__ rbT,
                                                    const float* __restrict__ att,
                                                    float* __restrict__ gemmT) {
    __shared__ unsigned short bS[2][64 * 128];    // [buf][o_local*128 + i_local] (xor-swizzled)
    __shared__ float attS[64][65];

    const int t = threadIdx.x;
    const int wv = t >> 6;
    const int ln = t & 63;
    const int q  = ln >> 4;     // quad 0..3
    const int lm = ln & 15;
    const int m0 = blockIdx.x * 64;
    const int o0 = blockIdx.y * 64;

    // stage att tile [64 m][64 n]
#pragma unroll
    for (int k = 0; k < 16; k++) {
        int idx = t + 256 * k;
        attS[idx >> 6][idx & 63] = att[(size_t)(m0 + (idx >> 6)) * 64 + (idx & 63)];
    }

    // async stage of one 64o x 128i bf16 tile (16 KiB = 16 chunks of 1 KiB; 4 per wave)
    auto stage = [&](int s, int buf) {
        int ic = s >> 6, n = s & 63;
#pragma unroll
        for (int j = 0; j < 4; j++) {
            int c   = wv * 4 + j;                 // chunk 0..15
            int r   = c * 4 + q;                  // o_local 0..63
            int c16 = (ln & 15) ^ (r & 15);       // logical i-chunk for this lane's slot
            const unsigned short* g = rbT + (size_t)(n * 512 + o0 + r) * 512 + ic * 128 + c16 * 8;
            void* l = (char*)(&bS[buf][0]) + c * 1024;
            __builtin_amdgcn_global_load_lds((const __attribute__((address_space(1))) void*)g,
                                             (__attribute__((address_space(3))) void*)l,
                                             16, 0, 0);
        }
    };

    f4 acc[4] = {f4{0,0,0,0}, f4{0,0,0,0}, f4{0,0,0,0}, f4{0,0,0,0}};
    s8 embF[4][4];

    stage(0, 0);

    for (int s = 0; s < 256; s++) {
        int ic = s >> 6, n = s & 63;
        if (n == 0) {
            // emb fragments for this i-chunk: register-resident across the whole n loop
#pragma unroll
            for (int ks = 0; ks < 4; ks++)
#pragma unroll
                for (int ms = 0; ms < 4; ms++)
                    embF[ks][ms] = *(const s8*)(embB + (size_t)(m0 + ms * 16 + lm) * 512
                                                + ic * 128 + ks * 32 + q * 8);
        }
        __syncthreads();                          // drains tile s loads; protects buffers
        if (s + 1 < 256) stage(s + 1, (s + 1) & 1);

        const unsigned short* bp = &bS[s & 1][0];
        f4 an[4] = {f4{0,0,0,0}, f4{0,0,0,0}, f4{0,0,0,0}, f4{0,0,0,0}};
#pragma unroll
        for (int ks = 0; ks < 4; ks++) {
            int c16 = (ks * 4 + q) ^ lm;          // un-swizzle
            s8 aF = *(const s8*)(bp + (wv * 16 + lm) * 128 + c16 * 8);
#pragma unroll
            for (int ms = 0; ms < 4; ms++)
                an[ms] = __builtin_amdgcn_mfma_f32_16x16x32_bf16(aF, embF[ks][ms], an[ms], 0, 0, 0);
        }
#pragma unroll
        for (int ms = 0; ms < 4; ms++) {
            float av = attS[ms * 16 + lm][n];     // broadcast within quad
            acc[ms] += av * an[ms];
        }
    }

    // epilogue: D[row=o][col=m]
#pragma unroll
    for (int ms = 0; ms < 4; ms++)
#pragma unroll
        for (int r = 0; r < 4; r++) {
            int o = o0 + wv * 16 + q * 4 + r;
            int m = m0 + ms * 16 + lm;
            gemmT[(size_t)o * 4096 + m] = acc[ms][r];
        }
}

// LayerNorm over o (512) per b; reads gemmT+biasT in [o][b] layout, writes out[b][o]
__global__ __launch_bounds__(256) void ln_kernel(const float* __restrict__ gT,
                                                 const float* __restrict__ bT,
                                                 float* __restrict__ out) {
    __shared__ float S[512][17];
    int t = threadIdx.x;
    int b0 = blockIdx.x * 16;
#pragma unroll
    for (int p = 0; p < 8; p++) {
        int r = p * 64 + (t >> 2);
        int cb = (t & 3) * 4;
        f4 g = *(const f4*)(gT + (size_t)r * 4096 + b0 + cb);
        f4 bb = *(const f4*)(bT + (size_t)r * 4096 + b0 + cb);
        f4 v = g + bb;
        S[r][cb + 0] = v[0]; S[r][cb + 1] = v[1]; S[r][cb + 2] = v[2]; S[r][cb + 3] = v[3];
    }
    __syncthreads();
    int b = t >> 4, j = t & 15;
    float s1 = 0.f, s2 = 0.f;
#pragma unroll
    for (int k = 0; k < 32; k++) {
        float v = S[j + 16 * k][b];
        s1 += v; s2 += v * v;
    }
#pragma unroll
    for (int off = 8; off; off >>= 1) {
        s1 += __shfl_down(s1, off, 16);
        s2 += __shfl_down(s2, off, 16);
    }
    int src = (t & 63) & ~15;
    s1 = __shfl(s1, src, 64);
    s2 = __shfl(s2, src, 64);
    float mu = s1 * (1.f / 512.f);
    float var = s2 * (1.f / 512.f) - mu * mu;
    float rs = rsqrtf(var + 1e-5f);
#pragma unroll
    for (int k = 0; k < 32; k++) {
        int o = j + 16 * k;
        out[(size_t)(b0 + b) * 512 + o] = (S[o][b] - mu) * rs;
    }
}

extern "C" void kernel_launch(void* const* d_in, const int* in_sizes, int n_in,
                              void* d_out, int out_size, void* d_ws, size_t ws_size,
                              hipStream_t stream) {
    (void)in_sizes; (void)n_in; (void)out_size; (void)ws_size;
    const float* emb      = (const float*)d_in[0];
    const int*   proj_ids = (const int*)d_in[1];
    const float* rel_att  = (const float*)d_in[2];
    const float* rel_base = (const float*)d_in[3];
    const float* rel_bias = (const float*)d_in[4];
    float* out = (float*)d_out;

    char* w = (char*)d_ws;
    float*          att   = (float*)(w);
    unsigned short* embB  = (unsigned short*)(w + (1u << 20));
    unsigned short* rbT   = (unsigned short*)(w + 5u * (1u << 20));
    float*          gemmT = (float*)(w + 37u * (1u << 20));
    float*          biasT = (float*)(w + 45u * (1u << 20));

    gather_att<<<dim3(1024), dim3(256), 0, stream>>>(proj_ids, rel_att, att);
    cvt_emb<<<dim3(2048), dim3(256), 0, stream>>>(emb, embB);
    transpose_rb<<<dim3(16, 16, 64), dim3(32, 8, 1), 0, stream>>>(rel_base, rbT);
    bias_kernel<<<dim3(64, 4), dim3(256), 0, stream>>>(att, rel_bias, biasT);
    gemm_fold<<<dim3(64, 8), dim3(256), 0, stream>>>(embB, rbT, att, gemmT);
    ln_kernel<<<dim3(256), dim3(256), 0, stream>>>(gemmT, biasT, out);
}

// Round 2
// 347.790 us; speedup vs baseline: 1.2531x; 1.2531x over previous
//
#include <hip/hip_runtime.h>

typedef float f4 __attribute__((ext_vector_type(4)));
typedef short s8 __attribute__((ext_vector_type(8)));
typedef unsigned short u16x4 __attribute__((ext_vector_type(4)));

// ---- ws layout (bytes) ----
// att    : 0        .. 1 MiB   (4096*64 f32)
// embB   : 1 MiB    .. 5 MiB   (4096*512 bf16)
// rbT    : 5 MiB    .. 37 MiB  (64*512*512 bf16, [n][o][i])
// gemmT  : 37 MiB   .. 53 MiB  (2 slices of 512*4096 f32, [o][b])

__device__ __forceinline__ unsigned short f2bf(float f) {
    unsigned int u = __float_as_uint(f);
    unsigned int r = (u + 0x7fffu + ((u >> 16) & 1u)) >> 16;
    return (unsigned short)r;
}

__global__ void gather_att(const int* __restrict__ ids, const float* __restrict__ rel_att,
                           float* __restrict__ att) {
    int g = blockIdx.x * 256 + threadIdx.x;       // 0 .. 4096*64-1
    int b = g >> 6, n = g & 63;
    att[g] = rel_att[(size_t)ids[b] * 64 + n];
}

__global__ void cvt_emb(const float* __restrict__ e, unsigned short* __restrict__ eb) {
    int g = (blockIdx.x * 256 + threadIdx.x) * 4;
    f4 v = *(const f4*)(e + g);
    u16x4 o;
    o[0] = f2bf(v[0]); o[1] = f2bf(v[1]); o[2] = f2bf(v[2]); o[3] = f2bf(v[3]);
    *(u16x4*)(eb + g) = o;
}

// rbT[n][o][i] = bf16(rel_base[n][i][o])
__global__ void transpose_rb(const float* __restrict__ rb, unsigned short* __restrict__ rbT) {
    __shared__ float tl[32][33];
    int n = blockIdx.z, i0 = blockIdx.x * 32, o0 = blockIdx.y * 32;
    int tx = threadIdx.x, ty = threadIdx.y;      // 32 x 8
#pragma unroll
    for (int k = 0; k < 4; k++) {
        int i = ty + k * 8;
        tl[i][tx] = rb[((size_t)(n * 512 + i0 + i)) * 512 + o0 + tx];
    }
    __syncthreads();
#pragma unroll
    for (int k = 0; k < 4; k++) {
        int o = ty + k * 8;
        rbT[((size_t)(n * 512 + o0 + o)) * 512 + i0 + tx] = f2bf(tl[tx][o]);
    }
}

// Main fused GEMM, n-split x2:
// gemmT[z][o][b] = sum_{n in half z} att[b,n] * sum_i emb[b,i]*rbT[n][o][i]
// block: 64 b (m) x 64 o; 4 waves, wave tile = 16 o x 64 m; K-chunks of 128 i.
// LDS = 32 KiB dbuf + 8 KiB attS = 40960 B exactly -> 4 blocks/CU.
__global__ __launch_bounds__(256, 4) void gemm_fold(const unsigned short* __restrict__ embB,
                                                    const unsigned short* __restrict__ rbT,
                                                    const float* __restrict__ att,
                                                    float* __restrict__ gemmT) {
    __shared__ unsigned short bS[2][64 * 128];    // [buf][o_local*128 + i_local] (xor-swizzled)
    __shared__ float attS[64][32];                // [m][n ^ (m&31)] swizzle, no pad

    const int t = threadIdx.x;
    const int wv = t >> 6;
    const int ln = t & 63;
    const int q  = ln >> 4;     // quad 0..3
    const int lm = ln & 15;
    const int m0 = blockIdx.x * 64;
    const int o0 = blockIdx.y * 64;
    const int nz = blockIdx.z;                    // n-half 0/1
    const int nbase = nz * 32;

    // stage att tile [64 m][32 n] (swizzled): 2048 floats, 8 per thread
#pragma unroll
    for (int k = 0; k < 8; k++) {
        int idx = t + 256 * k;
        int m = idx >> 5, n = idx & 31;
        attS[m][n ^ (m & 31)] = att[(size_t)(m0 + m) * 64 + nbase + n];
    }

    // async stage of one 64o x 128i bf16 tile (16 KiB = 16 chunks of 1 KiB; 4 per wave)
    auto stage = [&](int s, int buf) {
        int ic = s >> 5, n = nbase + (s & 31);
#pragma unroll
        for (int j = 0; j < 4; j++) {
            int c   = wv * 4 + j;                 // chunk 0..15
            int r   = c * 4 + q;                  // o_local 0..63
            int c16 = (ln & 15) ^ (r & 15);       // logical i-chunk for this lane's slot
            const unsigned short* g = rbT + (size_t)(n * 512 + o0 + r) * 512 + ic * 128 + c16 * 8;
            void* l = (char*)(&bS[buf][0]) + c * 1024;
            __builtin_amdgcn_global_load_lds((const __attribute__((address_space(1))) void*)g,
                                             (__attribute__((address_space(3))) void*)l,
                                             16, 0, 0);
        }
    };

    f4 acc[4] = {f4{0,0,0,0}, f4{0,0,0,0}, f4{0,0,0,0}, f4{0,0,0,0}};
    s8 embF[4][4];

    stage(0, 0);

    for (int s = 0; s < 128; s++) {
        int ic = s >> 5, nl = s & 31;
        if (nl == 0) {
            // emb fragments for this i-chunk: register-resident across the whole n loop
#pragma unroll
            for (int ks = 0; ks < 4; ks++)
#pragma unroll
                for (int ms = 0; ms < 4; ms++)
                    embF[ks][ms] = *(const s8*)(embB + (size_t)(m0 + ms * 16 + lm) * 512
                                                + ic * 128 + ks * 32 + q * 8);
        }
        __syncthreads();                          // drains tile s loads; protects buffers
        if (s + 1 < 128) stage(s + 1, (s + 1) & 1);

        const unsigned short* bp = &bS[s & 1][0];
        f4 an[4] = {f4{0,0,0,0}, f4{0,0,0,0}, f4{0,0,0,0}, f4{0,0,0,0}};
#pragma unroll
        for (int ks = 0; ks < 4; ks++) {
            int c16 = (ks * 4 + q) ^ lm;          // un-swizzle
            s8 aF = *(const s8*)(bp + (wv * 16 + lm) * 128 + c16 * 8);
#pragma unroll
            for (int ms = 0; ms < 4; ms++)
                an[ms] = __builtin_amdgcn_mfma_f32_16x16x32_bf16(aF, embF[ks][ms], an[ms], 0, 0, 0);
        }
#pragma unroll
        for (int ms = 0; ms < 4; ms++) {
            int row = ms * 16 + lm;
            float av = attS[row][nl ^ (row & 31)];   // broadcast within quad
            acc[ms] += av * an[ms];
        }
    }

    // epilogue: D[row=o][col=m] into this half's slice
    float* gT = gemmT + (size_t)nz * 512 * 4096;
#pragma unroll
    for (int ms = 0; ms < 4; ms++)
#pragma unroll
        for (int r = 0; r < 4; r++) {
            int o = o0 + wv * 16 + q * 4 + r;
            int m = m0 + ms * 16 + lm;
            gT[(size_t)o * 4096 + m] = acc[ms][r];
        }
}

// LayerNorm over o (512) per b: v = g0+g1+bias, bias computed in-kernel from
// att (LDS) x rel_bias (L2-resident, 128 KB). Writes out[b][o].
__global__ __launch_bounds__(256) void ln_kernel(const float* __restrict__ g0,
                                                 const float* __restrict__ g1,
                                                 const float* __restrict__ att,
                                                 const float* __restrict__ relb,
                                                 float* __restrict__ out) {
    __shared__ float S[512][17];
    __shared__ float attL[16][65];
    int t = threadIdx.x;
    int b0 = blockIdx.x * 16;

    {   // load att tile [16 b][64 n]: 1024 floats, 4 per thread
        int idx = t * 4;
        f4 v = *(const f4*)(att + (size_t)b0 * 64 + idx);
        int b = idx >> 6, n = idx & 63;
        attL[b][n] = v[0]; attL[b][n + 1] = v[1]; attL[b][n + 2] = v[2]; attL[b][n + 3] = v[3];
    }
    // phase 1: S[o][b] = g0 + g1
#pragma unroll
    for (int p = 0; p < 8; p++) {
        int r = p * 64 + (t >> 2);
        int cb = (t & 3) * 4;
        f4 a = *(const f4*)(g0 + (size_t)r * 4096 + b0 + cb);
        f4 b = *(const f4*)(g1 + (size_t)r * 4096 + b0 + cb);
        f4 v = a + b;
        S[r][cb + 0] = v[0]; S[r][cb + 1] = v[1]; S[r][cb + 2] = v[2]; S[r][cb + 3] = v[3];
    }
    __syncthreads();
    // phase 2: bias add. Thread owns (b = t>>4, o in [o0, o0+32)).
    {
        int bb = t >> 4;
        int o0 = (t & 15) * 32;
        float bias[32];
#pragma unroll
        for (int c = 0; c < 32; c++) bias[c] = 0.f;
        for (int n = 0; n < 64; n++) {
            float a = attL[bb][n];
            const f4* rp = (const f4*)(relb + n * 512 + o0);
#pragma unroll
            for (int c = 0; c < 8; c++) {
                f4 rv = rp[c];
                bias[4 * c + 0] += a * rv[0]; bias[4 * c + 1] += a * rv[1];
                bias[4 * c + 2] += a * rv[2]; bias[4 * c + 3] += a * rv[3];
            }
        }
#pragma unroll
        for (int c = 0; c < 32; c++) S[o0 + c][bb] += bias[c];
    }
    __syncthreads();
    // phase 3: LN
    int b = t >> 4, j = t & 15;
    float s1 = 0.f, s2 = 0.f;
#pragma unroll
    for (int k = 0; k < 32; k++) {
        float v = S[j + 16 * k][b];
        s1 += v; s2 += v * v;
    }
#pragma unroll
    for (int off = 8; off; off >>= 1) {
        s1 += __shfl_down(s1, off, 16);
        s2 += __shfl_down(s2, off, 16);
    }
    int src = (t & 63) & ~15;
    s1 = __shfl(s1, src, 64);
    s2 = __shfl(s2, src, 64);
    float mu = s1 * (1.f / 512.f);
    float var = s2 * (1.f / 512.f) - mu * mu;
    float rs = rsqrtf(var + 1e-5f);
#pragma unroll
    for (int k = 0; k < 32; k++) {
        int o = j + 16 * k;
        out[(size_t)(b0 + b) * 512 + o] = (S[o][b] - mu) * rs;
    }
}

extern "C" void kernel_launch(void* const* d_in, const int* in_sizes, int n_in,
                              void* d_out, int out_size, void* d_ws, size_t ws_size,
                              hipStream_t stream) {
    (void)in_sizes; (void)n_in; (void)out_size; (void)ws_size;
    const float* emb      = (const float*)d_in[0];
    const int*   proj_ids = (const int*)d_in[1];
    const float* rel_att  = (const float*)d_in[2];
    const float* rel_base = (const float*)d_in[3];
    const float* rel_bias = (const float*)d_in[4];
    float* out = (float*)d_out;

    char* w = (char*)d_ws;
    float*          att   = (float*)(w);
    unsigned short* embB  = (unsigned short*)(w + (1u << 20));
    unsigned short* rbT   = (unsigned short*)(w + 5u * (1u << 20));
    float*          gemmT = (float*)(w + 37u * (1u << 20));   // 2 slices of 8 MiB
    float*          g1    = gemmT + (size_t)512 * 4096;

    gather_att<<<dim3(1024), dim3(256), 0, stream>>>(proj_ids, rel_att, att);
    cvt_emb<<<dim3(2048), dim3(256), 0, stream>>>(emb, embB);
    transpose_rb<<<dim3(16, 16, 64), dim3(32, 8, 1), 0, stream>>>(rel_base, rbT);
    gemm_fold<<<dim3(64, 8, 2), dim3(256), 0, stream>>>(embB, rbT, att, gemmT);
    ln_kernel<<<dim3(256), dim3(256), 0, stream>>>(gemmT, g1, att, rel_bias, out);
}